// Round 1
// baseline (100.095 us; speedup 1.0000x reference)
//
#include <hip/hip_runtime.h>

#define BATCH 512
#define DIN 512
#define NCLS 16
#define NNODES 100000

// ---- workspace layout (bytes) ----
// best:         [0, 4096)        512 x u64 packed (sim, ~idx)
// probs:        [4096, 36864)    512 x 16 f32
// emb:          [36864, 40960)   512 x 2 f32
// bucket_count: [40960, 41024)   16 x i32
// bucket_list:  [41024, 73792)   16 x 512 i32
#define WS_BEST   0
#define WS_PROBS  4096
#define WS_EMB    36864
#define WS_BCNT   40960
#define WS_BLST   41024

__device__ __forceinline__ unsigned ford(float f) {
    unsigned bits = __float_as_uint(f);
    return (bits & 0x80000000u) ? ~bits : (bits | 0x80000000u);
}

// One block (64 threads) per sample.
__global__ __launch_bounds__(64) void prep_kernel(
    const float* __restrict__ logits,
    const float* __restrict__ train_data,
    const float* __restrict__ W,
    const float* __restrict__ bvec,
    float* __restrict__ probs,
    float* __restrict__ emb,
    int* __restrict__ bucket_count,
    int* __restrict__ bucket_list,
    unsigned long long* __restrict__ best) {
    const int s = blockIdx.x;
    const int lane = threadIdx.x;

    // emb = train_data[s] @ W + b   (W is [512,2] row-major -> float2 per k)
    float acc0 = 0.f, acc1 = 0.f;
    const float* td = train_data + s * DIN;
    const float2* W2 = (const float2*)W;
    for (int k = lane; k < DIN; k += 64) {
        float t = td[k];
        float2 w = W2[k];
        acc0 += t * w.x;
        acc1 += t * w.y;
    }
    for (int off = 32; off; off >>= 1) {
        acc0 += __shfl_down(acc0, off);
        acc1 += __shfl_down(acc1, off);
    }

    if (lane == 0) {
        emb[2 * s]     = acc0 + bvec[0];
        emb[2 * s + 1] = acc1 + bvec[1];

        // softmax over 16 logits + argmax (first-max tie-break)
        float l[NCLS];
        float m = -1e30f;
        int pred = 0;
        for (int j = 0; j < NCLS; ++j) {
            l[j] = logits[s * NCLS + j];
            if (l[j] > m) { m = l[j]; pred = j; }
        }
        float sum = 0.f;
        for (int j = 0; j < NCLS; ++j) { l[j] = expf(l[j] - m); sum += l[j]; }
        float inv = 1.0f / sum;
        for (int j = 0; j < NCLS; ++j) probs[s * NCLS + j] = l[j] * inv;

        int pos = atomicAdd(&bucket_count[pred], 1);
        bucket_list[pred * BATCH + pos] = s;
        best[s] = 0ull;  // packed value strictly below any finite sim
    }
}

// Grid-strided over nodes; one node per thread per iteration.
__global__ __launch_bounds__(256) void nodes_kernel(
    const float* __restrict__ all_nodes,
    const float* __restrict__ probs,
    const int* __restrict__ bucket_count,
    const int* __restrict__ bucket_list,
    unsigned long long* __restrict__ best) {
    __shared__ float sprobs[BATCH * NCLS];          // 32 KB
    __shared__ int scount[NCLS];
    __shared__ unsigned long long lbest[BATCH];     // 4 KB

    const int t = threadIdx.x;

    // stage probs into LDS (float4 coalesced)
    for (int i = t; i < BATCH * NCLS / 4; i += 256)
        ((float4*)sprobs)[i] = ((const float4*)probs)[i];
    if (t < NCLS) scount[t] = bucket_count[t];
    for (int i = t; i < BATCH; i += 256) lbest[i] = 0ull;
    __syncthreads();

    const int n = blockIdx.x * 256 + t;
    if (n < NNODES) {
        const float4* nv = (const float4*)(all_nodes + n * NCLS);
        float4 v0 = nv[0], v1 = nv[1], v2 = nv[2], v3 = nv[3];
        float vals[NCLS] = {v0.x, v0.y, v0.z, v0.w, v1.x, v1.y, v1.z, v1.w,
                            v2.x, v2.y, v2.z, v2.w, v3.x, v3.y, v3.z, v3.w};
        // node class = argmax (first-max tie-break), node norm
        int cls = 0;
        float m = vals[0];
        float nrm2 = 0.f;
        #pragma unroll
        for (int j = 0; j < NCLS; ++j) {
            if (j > 0 && vals[j] > m) { m = vals[j]; cls = j; }
            nrm2 += vals[j] * vals[j];
        }
        float inv_norm = 1.0f / sqrtf(nrm2);

        const int cnt = scount[cls];
        const int* lst = bucket_list + cls * BATCH;
        for (int i = 0; i < cnt; ++i) {
            int s = lst[i];
            const float4* p4 = (const float4*)(sprobs + s * NCLS);
            float4 a0 = p4[0], a1 = p4[1], a2 = p4[2], a3 = p4[3];
            float dot = a0.x * v0.x + a0.y * v0.y + a0.z * v0.z + a0.w * v0.w
                      + a1.x * v1.x + a1.y * v1.y + a1.z * v1.z + a1.w * v1.w
                      + a2.x * v2.x + a2.y * v2.y + a2.z * v2.z + a2.w * v2.w
                      + a3.x * v3.x + a3.y * v3.y + a3.z * v3.z + a3.w * v3.w;
            float sim = dot * inv_norm;
            unsigned long long packed =
                ((unsigned long long)ford(sim) << 32) | (unsigned long long)(0xFFFFFFFFu - (unsigned)n);
            atomicMax(&lbest[s], packed);
        }
    }
    __syncthreads();
    for (int i = t; i < BATCH; i += 256)
        if (lbest[i]) atomicMax(&best[i], lbest[i]);
}

// Single block, 512 threads: gather targets, MSE, mean.
__global__ __launch_bounds__(512) void finalize_kernel(
    const unsigned long long* __restrict__ best,
    const float* __restrict__ emb,
    const float* __restrict__ all_nodes_2d,
    float* __restrict__ out) {
    const int s = threadIdx.x;
    unsigned long long p = best[s];
    int idx = (p == 0ull) ? 0 : (int)(0xFFFFFFFFu - (unsigned)(p & 0xFFFFFFFFull));
    float t0 = all_nodes_2d[2 * idx];
    float t1 = all_nodes_2d[2 * idx + 1];
    float d0 = emb[2 * s] - t0;
    float d1 = emb[2 * s + 1] - t1;
    float v = 0.5f * (d0 * d0 + d1 * d1);

    for (int off = 32; off; off >>= 1) v += __shfl_down(v, off);
    __shared__ float partial[8];
    if ((s & 63) == 0) partial[s >> 6] = v;
    __syncthreads();
    if (s == 0) {
        float sum = 0.f;
        for (int i = 0; i < 8; ++i) sum += partial[i];
        out[0] = sum / (float)BATCH;
    }
}

extern "C" void kernel_launch(void* const* d_in, const int* in_sizes, int n_in,
                              void* d_out, int out_size, void* d_ws, size_t ws_size,
                              hipStream_t stream) {
    const float* logits       = (const float*)d_in[0];
    const float* train_data   = (const float*)d_in[1];
    const float* all_nodes    = (const float*)d_in[2];
    const float* all_nodes_2d = (const float*)d_in[3];
    const float* W            = (const float*)d_in[4];
    const float* bvec         = (const float*)d_in[5];
    float* out = (float*)d_out;

    char* ws = (char*)d_ws;
    unsigned long long* best = (unsigned long long*)(ws + WS_BEST);
    float* probs             = (float*)(ws + WS_PROBS);
    float* emb               = (float*)(ws + WS_EMB);
    int* bucket_count        = (int*)(ws + WS_BCNT);
    int* bucket_list         = (int*)(ws + WS_BLST);

    // zero the bucket counts (ws is poisoned 0xAA before every call)
    hipMemsetAsync(bucket_count, 0, NCLS * sizeof(int), stream);

    prep_kernel<<<BATCH, 64, 0, stream>>>(logits, train_data, W, bvec,
                                          probs, emb, bucket_count, bucket_list, best);

    int nblocks = (NNODES + 255) / 256;
    nodes_kernel<<<nblocks, 256, 0, stream>>>(all_nodes, probs, bucket_count,
                                              bucket_list, best);

    finalize_kernel<<<1, BATCH, 0, stream>>>(best, emb, all_nodes_2d, out);
}